// Round 3
// baseline (236.189 us; speedup 1.0000x reference)
//
#include <hip/hip_runtime.h>

// EMA along T for [B=8, C=64, F=128, T=2000] fp32.
// One 64-lane wave per (b,c,f) row. Each lane owns 8 consecutive elements
// (2x float4), so T is covered by 4 chunks of 512 (last chunk = 464 = 58x8,
// every active lane still owns a FULL 8-elem segment). All loads hoisted
// up-front (16 KB in flight per wave), then 4 wave-level Kogge-Stone
// linear-recurrence scans (6 shfl steps each) run as pure VALU work.

typedef float f32x4 __attribute__((ext_vector_type(4)));

#define T_LEN 2000
#define NROWS 65536   // 8*64*128
#define C_DIM 64
#define NCHUNK 4      // chunks of 512 = 64 lanes x 8
#define TAIL_LANES 58 // (2000 - 3*512)/8

__global__ __launch_bounds__(256) void ema_scan_kernel(
    const float* __restrict__ x,       // [NROWS][T_LEN]
    const float* __restrict__ init,    // [NROWS]
    const float* __restrict__ weights, // [C_DIM]
    float* __restrict__ out,           // [NROWS][T_LEN]
    float* __restrict__ final_out)     // [NROWS]
{
    const int gwave = (blockIdx.x * blockDim.x + threadIdx.x) >> 6;
    const int lane  = threadIdx.x & 63;
    if (gwave >= NROWS) return;
    const int row = gwave;
    const int c   = (row >> 7) & (C_DIM - 1);   // row = ((b*C)+c)*F + f

    float w = weights[c];
    w = fminf(fmaxf(w, 0.0f), 1.0f);
    const float a = 1.0f - w;

    // Powers of a via repeated squaring.
    const float a2   = a * a;
    const float a4   = a2 * a2;
    const float a8   = a4 * a4;
    const float a16  = a8 * a8;
    const float a32  = a16 * a16;
    const float a64  = a32 * a32;
    const float a128 = a64 * a64;
    const float a256 = a128 * a128;
    const float a512 = a256 * a256;

    // a^(8*lane) from lane bits (constant across chunks).
    float pw = 1.0f;
    if (lane & 1)  pw *= a8;
    if (lane & 2)  pw *= a16;
    if (lane & 4)  pw *= a32;
    if (lane & 8)  pw *= a64;
    if (lane & 16) pw *= a128;
    if (lane & 32) pw *= a256;

    const float* __restrict__ xrow = x   + (long long)row * T_LEN;
    float* __restrict__       orow = out + (long long)row * T_LEN;
    const int tl = lane * 8;    // this lane's first element within a chunk

    // ---- Hoist ALL chunk loads: up to 8 outstanding 1KB wave-loads (nt).
    f32x4 lo[NCHUNK], hi[NCHUNK];
    #pragma unroll
    for (int i = 0; i < NCHUNK - 1; ++i) {
        lo[i] = __builtin_nontemporal_load(
                    reinterpret_cast<const f32x4*>(xrow + i * 512 + tl));
        hi[i] = __builtin_nontemporal_load(
                    reinterpret_cast<const f32x4*>(xrow + i * 512 + tl + 4));
    }
    if (lane < TAIL_LANES) {
        lo[NCHUNK - 1] = __builtin_nontemporal_load(
                    reinterpret_cast<const f32x4*>(xrow + (NCHUNK - 1) * 512 + tl));
        hi[NCHUNK - 1] = __builtin_nontemporal_load(
                    reinterpret_cast<const f32x4*>(xrow + (NCHUNK - 1) * 512 + tl + 4));
    } else {
        f32x4 z = {0.0f, 0.0f, 0.0f, 0.0f};
        lo[NCHUNK - 1] = z;
        hi[NCHUNK - 1] = z;
    }

    float acc = init[row];   // running state at chunk boundaries (wave-uniform)

    #pragma unroll
    for (int i = 0; i < NCHUNK; ++i) {
        const f32x4 xl = lo[i], xh = hi[i];

        // Local 8-elem segment reduce (FMA tree, depth 3):
        // B = w * sum_{j=0..7} a^(7-j) x_j
        const float y0 = fmaf(a, xl.x, xl.y);
        const float y1 = fmaf(a, xl.z, xl.w);
        const float y2 = fmaf(a, xh.x, xh.y);
        const float y3 = fmaf(a, xh.z, xh.w);
        const float z0 = fmaf(a2, y0, y1);
        const float z1 = fmaf(a2, y2, y3);
        float B = w * fmaf(a4, z0, z1);

        // Kogge-Stone inclusive scan over 64 lanes; at offset d the partial
        // covers 8d elements -> combine B = a^(8d)*B_up + B.
        float Bup;
        Bup = __shfl_up(B, 1);  if (lane >= 1)  B = fmaf(a8,   Bup, B);
        Bup = __shfl_up(B, 2);  if (lane >= 2)  B = fmaf(a16,  Bup, B);
        Bup = __shfl_up(B, 4);  if (lane >= 4)  B = fmaf(a32,  Bup, B);
        Bup = __shfl_up(B, 8);  if (lane >= 8)  B = fmaf(a64,  Bup, B);
        Bup = __shfl_up(B, 16); if (lane >= 16) B = fmaf(a128, Bup, B);
        Bup = __shfl_up(B, 32); if (lane >= 32) B = fmaf(a256, Bup, B);

        // Exclusive prefix for this lane.
        float Bexcl = __shfl_up(B, 1);
        if (lane == 0) Bexcl = 0.0f;

        // State entering this lane's 8-elem segment.
        float accl = fmaf(pw, acc, Bexcl);

        // Serial epilogue: per-element outputs.
        f32x4 ol, oh;
        accl = fmaf(a, accl, w * xl.x); ol.x = accl;
        accl = fmaf(a, accl, w * xl.y); ol.y = accl;
        accl = fmaf(a, accl, w * xl.z); ol.z = accl;
        accl = fmaf(a, accl, w * xl.w); ol.w = accl;
        accl = fmaf(a, accl, w * xh.x); oh.x = accl;
        accl = fmaf(a, accl, w * xh.y); oh.y = accl;
        accl = fmaf(a, accl, w * xh.z); oh.z = accl;
        accl = fmaf(a, accl, w * xh.w); oh.w = accl;

        if (i < NCHUNK - 1) {
            __builtin_nontemporal_store(ol,
                reinterpret_cast<f32x4*>(orow + i * 512 + tl));
            __builtin_nontemporal_store(oh,
                reinterpret_cast<f32x4*>(orow + i * 512 + tl + 4));
            // Carry to next chunk (wave-uniform).
            const float Btop = __shfl(B, 63);
            acc = fmaf(a512, acc, Btop);
        } else if (lane < TAIL_LANES) {
            __builtin_nontemporal_store(ol,
                reinterpret_cast<f32x4*>(orow + (NCHUNK - 1) * 512 + tl));
            __builtin_nontemporal_store(oh,
                reinterpret_cast<f32x4*>(orow + (NCHUNK - 1) * 512 + tl + 4));
            if (lane == TAIL_LANES - 1) final_out[row] = accl;
        }
    }
}

extern "C" void kernel_launch(void* const* d_in, const int* in_sizes, int n_in,
                              void* d_out, int out_size, void* d_ws, size_t ws_size,
                              hipStream_t stream) {
    const float* mag  = (const float*)d_in[0];   // [8,64,128,2000]
    const float* init = (const float*)d_in[1];   // [8,64,128,1]
    const float* wgt  = (const float*)d_in[2];   // [64]
    float* out = (float*)d_out;                  // [8,64,128,2000] then [8,64,128,1]
    float* fin = out + (long long)NROWS * T_LEN;

    const int threads = 256;                 // 4 waves/block -> 4 rows/block
    const int blocks  = NROWS / 4;           // 16384
    ema_scan_kernel<<<blocks, threads, 0, stream>>>(mag, init, wgt, out, fin);
}

// Round 4
// 180.230 us; speedup vs baseline: 1.3105x; 1.3105x over previous
//
#include <hip/hip_runtime.h>

// EMA along T for [B=8, C=64, F=128, T=2000] fp32.
// One 64-lane wave per (b,c,f) row. T covered by 8 chunks of 256 elems
// (last chunk 208 = 52 lanes x 4: every active lane loads a FULL float4,
// and each load/store instruction tiles cache lines exactly -- 4 elems/lane
// is the coalescing sweet spot; 8 elems/lane regressed 31% in R3).
// All 8 chunk loads hoisted up-front (8 KB in flight per wave), then 8
// wave-level Kogge-Stone linear-recurrence scans run as pure VALU work.
// Carry broadcast uses v_readlane (scalar) instead of ds_bpermute.

typedef float f32x4 __attribute__((ext_vector_type(4)));

#define T_LEN 2000
#define NROWS 65536   // 8*64*128
#define C_DIM 64
#define NCHUNK 8
#define TAIL_LANES 52 // (2000 - 7*256)/4

__global__ __launch_bounds__(256) void ema_scan_kernel(
    const float* __restrict__ x,       // [NROWS][T_LEN]
    const float* __restrict__ init,    // [NROWS]
    const float* __restrict__ weights, // [C_DIM]
    float* __restrict__ out,           // [NROWS][T_LEN]
    float* __restrict__ final_out)     // [NROWS]
{
    const int gwave = (blockIdx.x * blockDim.x + threadIdx.x) >> 6;
    const int lane  = threadIdx.x & 63;
    if (gwave >= NROWS) return;
    const int row = gwave;
    const int c   = (row >> 7) & (C_DIM - 1);   // row = ((b*C)+c)*F + f

    float w = weights[c];
    w = fminf(fmaxf(w, 0.0f), 1.0f);
    const float a = 1.0f - w;

    // Powers of a via repeated squaring.
    const float a2   = a * a;
    const float a3   = a2 * a;
    const float a4   = a2 * a2;
    const float a8   = a4 * a4;
    const float a16  = a8 * a8;
    const float a32  = a16 * a16;
    const float a64  = a32 * a32;
    const float a128 = a64 * a64;
    const float a256 = a128 * a128;

    // a^(4*lane) from lane bits (constant across chunks).
    float pw = 1.0f;
    if (lane & 1)  pw *= a4;
    if (lane & 2)  pw *= a8;
    if (lane & 4)  pw *= a16;
    if (lane & 8)  pw *= a32;
    if (lane & 16) pw *= a64;
    if (lane & 32) pw *= a128;

    const float* __restrict__ xrow = x   + (long long)row * T_LEN;
    float* __restrict__       orow = out + (long long)row * T_LEN;
    const int tl = lane * 4;

    // ---- Hoist ALL chunk loads: 8 outstanding 1KB wave-loads (streamed, nt).
    f32x4 v[NCHUNK];
    #pragma unroll
    for (int i = 0; i < NCHUNK - 1; ++i)
        v[i] = __builtin_nontemporal_load(
                   reinterpret_cast<const f32x4*>(xrow + i * 256 + tl));
    if (lane < TAIL_LANES)
        v[NCHUNK - 1] = __builtin_nontemporal_load(
                   reinterpret_cast<const f32x4*>(xrow + (NCHUNK - 1) * 256 + tl));
    else {
        f32x4 z = {0.0f, 0.0f, 0.0f, 0.0f};
        v[NCHUNK - 1] = z;
    }

    float acc = init[row];   // running state at chunk boundaries (wave-uniform)

    #pragma unroll
    for (int i = 0; i < NCHUNK; ++i) {
        const f32x4 xv = v[i];

        // Local 4-elem segment reduce: B = w*(a^3 x0 + a^2 x1 + a x2 + x3)
        float B = w * fmaf(a3, xv.x, fmaf(a2, xv.y, fmaf(a, xv.z, xv.w)));

        // Kogge-Stone inclusive scan over 64 lanes; combine B = a^(4d)*B_up + B.
        float Bup;
        Bup = __shfl_up(B, 1);  if (lane >= 1)  B = fmaf(a4,   Bup, B);
        Bup = __shfl_up(B, 2);  if (lane >= 2)  B = fmaf(a8,   Bup, B);
        Bup = __shfl_up(B, 4);  if (lane >= 4)  B = fmaf(a16,  Bup, B);
        Bup = __shfl_up(B, 8);  if (lane >= 8)  B = fmaf(a32,  Bup, B);
        Bup = __shfl_up(B, 16); if (lane >= 16) B = fmaf(a64,  Bup, B);
        Bup = __shfl_up(B, 32); if (lane >= 32) B = fmaf(a128, Bup, B);

        // Exclusive prefix for this lane.
        float Bexcl = __shfl_up(B, 1);
        if (lane == 0) Bexcl = 0.0f;

        // State entering this lane's segment.
        float accl = fmaf(pw, acc, Bexcl);

        // Serial epilogue: reconstruct per-element outputs.
        f32x4 o;
        accl = fmaf(a, accl, w * xv.x); o.x = accl;
        accl = fmaf(a, accl, w * xv.y); o.y = accl;
        accl = fmaf(a, accl, w * xv.z); o.z = accl;
        accl = fmaf(a, accl, w * xv.w); o.w = accl;

        if (i < NCHUNK - 1) {
            __builtin_nontemporal_store(o,
                reinterpret_cast<f32x4*>(orow + i * 256 + tl));
            // Carry to next chunk: wave-uniform broadcast via v_readlane
            // (scalar pipe) instead of ds_bpermute.
            const int  Bbits = __builtin_amdgcn_readlane(__float_as_int(B), 63);
            const float Btop = __int_as_float(Bbits);
            acc = fmaf(a256, acc, Btop);
        } else if (lane < TAIL_LANES) {
            __builtin_nontemporal_store(o,
                reinterpret_cast<f32x4*>(orow + (NCHUNK - 1) * 256 + tl));
            if (lane == TAIL_LANES - 1) final_out[row] = accl;
        }
    }
}

extern "C" void kernel_launch(void* const* d_in, const int* in_sizes, int n_in,
                              void* d_out, int out_size, void* d_ws, size_t ws_size,
                              hipStream_t stream) {
    const float* mag  = (const float*)d_in[0];   // [8,64,128,2000]
    const float* init = (const float*)d_in[1];   // [8,64,128,1]
    const float* wgt  = (const float*)d_in[2];   // [64]
    float* out = (float*)d_out;                  // [8,64,128,2000] then [8,64,128,1]
    float* fin = out + (long long)NROWS * T_LEN;

    const int threads = 256;                 // 4 waves/block -> 4 rows/block
    const int blocks  = NROWS / 4;           // 16384
    ema_scan_kernel<<<blocks, threads, 0, stream>>>(mag, init, wgt, out, fin);
}